// Round 12
// baseline (340.599 us; speedup 1.0000x reference)
//
#include <hip/hip_runtime.h>
#include <cstdint>
#include <cmath>

#define MB (1024ull * 1024ull)

typedef unsigned short u16;
typedef __attribute__((ext_vector_type(8))) short short8;
typedef __attribute__((ext_vector_type(4))) float f32x4;

enum { M_EMA = 0, M_ZRE = 1, M_QKVF = 2, M_SCALE = 3, M_PVMUL = 4, M_F32 = 5 };

__device__ __forceinline__ u16 f2b(float f) {
  union { float f; uint32_t u; } v; v.f = f;
  uint32_t r = v.u + 0x7FFFu + ((v.u >> 16) & 1u);
  return (u16)(r >> 16);
}
__device__ __forceinline__ float b2f(u16 u) {
  union { uint32_t u; float f; } v; v.u = ((uint32_t)u) << 16;
  return v.f;
}
__device__ __forceinline__ float tanh_fast(float x) {
  return 1.f - 2.f / (1.f + __expf(2.f * x));
}
__device__ __forceinline__ float sigmoid_fast(float x) {
  return 1.f / (1.f + __expf(-x));
}

typedef __attribute__((address_space(3))) uint32_t lds_u32;
typedef const __attribute__((address_space(1))) uint32_t glb_u32;

__device__ __forceinline__ void gload16(const void* g, void* l) {
  __builtin_amdgcn_global_load_lds((glb_u32*)g, (lds_u32*)l, 16, 0, 0);
}

// ---------------- MFMA GEMM: C = epi(A @ B^T [+ bias]) ----------------
// 64 x 128 tile, 4 waves (1x4, 64r x 32c each), BK=64, 2-buffer LDS (48 KB),
// stage(t+1) issued before compute(t), ONE __syncthreads per K-step.
// BK=64 -> 16 MFMA per wave per barrier (2x round-11's 8): halves barrier count.
// LDS swizzle (rule 21, both sides): physical 16B-chunk p of row r holds logical
// chunk p ^ (r&7); applied at the global source AND the ds_read address.
// M_EMA: Wad/bias interleaved (alpha even col, delta odd col); epilogue pairs
//        lanes via shfl_xor(1); even lane computes REMA from R (fp32) -> Cb bf16.
// M_QKVF: virtual N=4096; bn>=3072 computes f=sigmoid(A2@B2^T+bias2) -> Cb3.
// M_PVMUL: epilogue v *= aux (f-gate) -> Cb.
template <int MODE>
__global__ __launch_bounds__(256) void gemm(const u16* __restrict__ A,
                                            const u16* __restrict__ B,
                                            const float* __restrict__ bias,
                                            const u16* __restrict__ A2,
                                            const u16* __restrict__ B2,
                                            const float* __restrict__ bias2,
                                            const u16* __restrict__ auxb,
                                            u16* __restrict__ Cb,
                                            u16* __restrict__ Cb2,
                                            u16* __restrict__ Cb3,
                                            float* __restrict__ Cf,
                                            const float* __restrict__ R,
                                            int K, int lda, int ldb, float scale) {
  constexpr int NI = 4;
  constexpr int NJ = 2;
  __shared__ u16 As[2][64 * 64];    // 8 KB per buffer
  __shared__ u16 Bs[2][128 * 64];   // 16 KB per buffer
  const int tid = threadIdx.x;
  const int wid = tid >> 6, lane = tid & 63;

  // XCD-aware bijective block swizzle (grids are multiples of 8)
  const int gx = gridDim.x, nwg = gx * gridDim.y;
  int id = blockIdx.y * gx + blockIdx.x;
  if ((nwg & 7) == 0) id = (id & 7) * (nwg >> 3) + (id >> 3);
  const int bm = (id / gx) * 64, bn = (id % gx) * 128;
  const int colbase = wid * 32;

  const bool isf = (MODE == M_QKVF) && (bn >= 3072);
  const u16* Ab = isf ? A2 : A;
  const u16* Bb = isf ? B2 : B;
  const int bnl = isf ? bn - 3072 : bn;

  f32x4 acc[NI][NJ];
#pragma unroll
  for (int i = 0; i < NI; ++i)
#pragma unroll
    for (int j = 0; j < NJ; ++j) acc[i][j] = (f32x4){0.f, 0.f, 0.f, 0.f};

  const int ar = lane & 15;
  const int kq = lane >> 4;  // 0..3: which 8-elem chunk within a K=32 half

  const int NT = K >> 6;

  // staging: A 64x64 = 512 slots (2 rounds), B 128x64 = 1024 slots (4 rounds).
  // slot -> row = slot>>3, phys chunk = slot&7; src logical chunk = phys ^ (row&7).
  auto stage = [&](int buf, int t) {
    const int kbase = t * 64;
#pragma unroll
    for (int l = 0; l < 2; ++l) {
      const int slot = l * 256 + tid;
      const int row = slot >> 3, ch = slot & 7;
      const u16* src = Ab + (size_t)(bm + row) * lda + kbase + ((ch ^ (row & 7)) << 3);
      gload16(src, &As[buf][slot * 8]);
    }
#pragma unroll
    for (int l = 0; l < 4; ++l) {
      const int slot = l * 256 + tid;
      const int row = slot >> 3, ch = slot & 7;
      const u16* src = Bb + (size_t)(bnl + row) * ldb + kbase + ((ch ^ (row & 7)) << 3);
      gload16(src, &Bs[buf][slot * 8]);
    }
  };

  stage(0, 0);
  __syncthreads();
  int cur = 0;
  for (int t = 0; t < NT; ++t) {
    if (t + 1 < NT) stage(cur ^ 1, t + 1);  // prefetch overlaps compute below
    short8 af[2][NI], bf[2][NJ];
#pragma unroll
    for (int kh = 0; kh < 2; ++kh) {
#pragma unroll
      for (int i = 0; i < NI; ++i) {
        const int row = i * 16 + ar;
        af[kh][i] = *reinterpret_cast<const short8*>(
            &As[cur][row * 64 + (((kh * 4 + kq) ^ (row & 7)) << 3)]);
      }
#pragma unroll
      for (int j = 0; j < NJ; ++j) {
        const int row = colbase + j * 16 + ar;
        bf[kh][j] = *reinterpret_cast<const short8*>(
            &Bs[cur][row * 64 + (((kh * 4 + kq) ^ (row & 7)) << 3)]);
      }
    }
    __builtin_amdgcn_s_setprio(1);
#pragma unroll
    for (int kh = 0; kh < 2; ++kh)
#pragma unroll
      for (int i = 0; i < NI; ++i)
#pragma unroll
        for (int j = 0; j < NJ; ++j)
          acc[i][j] = __builtin_amdgcn_mfma_f32_16x16x32_bf16(af[kh][i], bf[kh][j], acc[i][j], 0, 0, 0);
    __builtin_amdgcn_s_setprio(0);
    __syncthreads();
    cur ^= 1;
  }

#pragma unroll
  for (int i = 0; i < NI; ++i) {
    const int rb = bm + i * 16 + (lane >> 4) * 4;
#pragma unroll
    for (int j = 0; j < NJ; ++j) {
      const int n = bn + colbase + j * 16 + ar;
#pragma unroll
      for (int r = 0; r < 4; ++r) {
        const int m = rb + r;
        float v = acc[i][j][r];
        if (MODE == M_EMA) {
          v = tanh_fast(v + bias[n]);
          const float vp = __shfl_xor(v, 1);
          if ((lane & 1) == 0) {
            const int jc = n >> 1;
            const float rt = R[(size_t)m * 1024 + jc];
            const float rp = (m > 0) ? R[(size_t)(m - 1) * 1024 + jc] : 0.f;
            const float rema = v * rt + (1.f - v) * vp * rp;
            Cb[(size_t)m * 1024 + jc] = f2b(rema);
          }
        } else if (MODE == M_ZRE) {
          v += bias[n];
          if (n < 1024) Cb[(size_t)m * 1024 + n] = f2b(v * sigmoid_fast(v));
          else Cb2[(size_t)m * 1024 + (n - 1024)] = f2b(v);
        } else if (MODE == M_QKVF) {
          if (isf) {
            const int nl = n - 3072;
            Cb3[(size_t)m * 1024 + nl] = f2b(sigmoid_fast(v + bias2[nl]));
          } else {
            v += bias[n];
            if (n < 2048) Cb[(size_t)m * 2048 + n] = f2b(v);
            else Cb2[(size_t)m * 1024 + (n - 2048)] = f2b(v);
          }
        } else if (MODE == M_SCALE) {
          Cb[(size_t)m * 4096 + n] = f2b(v * scale);
        } else if (MODE == M_PVMUL) {
          v *= b2f(auxb[(size_t)m * 1024 + n]);
          Cb[(size_t)m * 1024 + n] = f2b(v);
        } else if (MODE == M_F32) {
          Cf[(size_t)m * 1024 + n] = v + bias[n];
        }
      }
    }
  }
}

// ---------------- merged prep: weight conversions (Wad interleaved) + concat ----------------
__global__ __launch_bounds__(256) void convert_all(
    const float* __restrict__ s0, const float* __restrict__ s1, const float* __restrict__ s2,
    const float* __restrict__ s3, const float* __restrict__ s4, const float* __restrict__ s5,
    const float* __restrict__ s6, const float* __restrict__ s7, const float* __restrict__ s8,
    const float* __restrict__ R,
    u16* __restrict__ Wad, u16* __restrict__ Wze, u16* __restrict__ Wqkv,
    u16* __restrict__ Wfb, u16* __restrict__ Wzab, u16* __restrict__ Rc) {
  const int idx = blockIdx.x * 256 + threadIdx.x;
  if (idx >= 2883584) {
    const int off = idx - 2883584;
    const int m = off >> 9;
    const int c = (off & 511) * 4;
    float4 v;
    if (c < 1024) {
      if (m > 0) v = *reinterpret_cast<const float4*>(&R[(size_t)(m - 1) * 1024 + c]);
      else v = make_float4(0.f, 0.f, 0.f, 0.f);
    } else {
      v = *reinterpret_cast<const float4*>(&R[(size_t)m * 1024 + (c - 1024)]);
    }
    ushort4 o; o.x = f2b(v.x); o.y = f2b(v.y); o.z = f2b(v.z); o.w = f2b(v.w);
    reinterpret_cast<ushort4*>(Rc)[off] = o;
    return;
  }
  const float* src; u16* dst; int off; int dstoff = -1;
  if (idx < 524288) {
    src = s0; dst = Wad; off = idx;
    dstoff = ((off >> 9) * 2) * 512 + (off & 511);
  } else if (idx < 1048576) {
    src = s1; dst = Wad; off = idx - 524288;
    dstoff = ((off >> 9) * 2 + 1) * 512 + (off & 511);
  }
  else if (idx < 1310720) { src = s2; dst = Wze;            off = idx - 1048576; }
  else if (idx < 1572864) { src = s3; dst = Wze + 1048576;  off = idx - 1310720; }
  else if (idx < 1835008) { src = s4; dst = Wqkv;           off = idx - 1572864; }
  else if (idx < 2097152) { src = s5; dst = Wqkv + 1048576; off = idx - 1835008; }
  else if (idx < 2359296) { src = s6; dst = Wqkv + 2097152; off = idx - 2097152; }
  else if (idx < 2621440) { src = s7; dst = Wfb;            off = idx - 2359296; }
  else                    { src = s8; dst = Wzab;           off = idx - 2621440; }
  if (dstoff < 0) dstoff = off;
  const float4 v = reinterpret_cast<const float4*>(src)[off];
  ushort4 o; o.x = f2b(v.x); o.y = f2b(v.y); o.z = f2b(v.z); o.w = f2b(v.w);
  reinterpret_cast<ushort4*>(dst)[dstoff] = o;
}

__global__ void copy_bias(const float* __restrict__ ba, const float* __restrict__ bd,
                          const float* __restrict__ bz, const float* __restrict__ be,
                          const float* __restrict__ bq, const float* __restrict__ bk,
                          const float* __restrict__ bv,
                          float* __restrict__ bad, float* __restrict__ bze,
                          float* __restrict__ bqkv) {
  const int t = threadIdx.x;
  if (blockIdx.x == 0) {
#pragma unroll
    for (int k = 0; k < 4; ++k) bad[2 * (t + 256 * k)] = ba[t + 256 * k];
    return;
  }
  if (blockIdx.x == 1) {
#pragma unroll
    for (int k = 0; k < 4; ++k) bad[2 * (t + 256 * k) + 1] = bd[t + 256 * k];
    return;
  }
  const float4* src; float4* dst;
  switch (blockIdx.x) {
    case 2: src = (const float4*)bz; dst = (float4*)bze; break;
    case 3: src = (const float4*)be; dst = (float4*)(bze + 1024); break;
    case 4: src = (const float4*)bq; dst = (float4*)bqkv; break;
    case 5: src = (const float4*)bk; dst = (float4*)(bqkv + 1024); break;
    default: src = (const float4*)bv; dst = (float4*)(bqkv + 2048); break;
  }
  dst[t] = src[t];
}

__device__ __forceinline__ float waveMax(float v) {
#pragma unroll
  for (int o = 32; o; o >>= 1) v = fmaxf(v, __shfl_down(v, o));
  return v;
}
__device__ __forceinline__ float waveSum(float v) {
#pragma unroll
  for (int o = 32; o; o >>= 1) v += __shfl_down(v, o);
  return v;
}

__global__ __launch_bounds__(256) void softmax_rows(u16* __restrict__ S) {
  u16* p = S + (size_t)blockIdx.x * 4096;
  const int tid = threadIdx.x;
  float v[16];
#pragma unroll
  for (int j = 0; j < 4; ++j) {
    const ushort4 t = *reinterpret_cast<const ushort4*>(&p[tid * 4 + 1024 * j]);
    v[4 * j + 0] = b2f(t.x); v[4 * j + 1] = b2f(t.y);
    v[4 * j + 2] = b2f(t.z); v[4 * j + 3] = b2f(t.w);
  }
  float mx = -INFINITY;
#pragma unroll
  for (int j = 0; j < 16; ++j) mx = fmaxf(mx, v[j]);
  __shared__ float red[4];
  const float wm = waveMax(mx);
  if ((tid & 63) == 0) red[tid >> 6] = wm;
  __syncthreads();
  mx = fmaxf(fmaxf(red[0], red[1]), fmaxf(red[2], red[3]));
  __syncthreads();
  float sum = 0.f;
#pragma unroll
  for (int j = 0; j < 16; ++j) { v[j] = __expf(v[j] - mx); sum += v[j]; }
  const float ws_ = waveSum(sum);
  if ((tid & 63) == 0) red[tid >> 6] = ws_;
  __syncthreads();
  const float inv = 1.f / (red[0] + red[1] + red[2] + red[3]);
#pragma unroll
  for (int j = 0; j < 4; ++j) {
    ushort4 t;
    t.x = f2b(v[4 * j + 0] * inv); t.y = f2b(v[4 * j + 1] * inv);
    t.z = f2b(v[4 * j + 2] * inv); t.w = f2b(v[4 * j + 3] * inv);
    *reinterpret_cast<ushort4*>(&p[tid * 4 + 1024 * j]) = t;
  }
}

__global__ __launch_bounds__(256) void transpose_b16(const u16* __restrict__ V,
                                                     u16* __restrict__ Vt) {
  __shared__ u16 t[64][72];
  const int bn = blockIdx.x * 64;
  const int bk = blockIdx.y * 64;
  const int tx = threadIdx.x & 15, ty = threadIdx.x >> 4;
#pragma unroll
  for (int i = 0; i < 64; i += 16) {
    const ushort4 v = *reinterpret_cast<const ushort4*>(&V[(size_t)(bk + ty + i) * 1024 + bn + tx * 4]);
    t[ty + i][tx * 4 + 0] = v.x; t[ty + i][tx * 4 + 1] = v.y;
    t[ty + i][tx * 4 + 2] = v.z; t[ty + i][tx * 4 + 3] = v.w;
  }
  __syncthreads();
#pragma unroll
  for (int i = 0; i < 64; i += 16) {
    ushort4 w;
    w.x = t[tx * 4 + 0][ty + i]; w.y = t[tx * 4 + 1][ty + i];
    w.z = t[tx * 4 + 2][ty + i]; w.w = t[tx * 4 + 3][ty + i];
    *reinterpret_cast<ushort4*>(&Vt[(size_t)(bn + ty + i) * 4096 + bk + tx * 4]) = w;
  }
}

// fused: i = tanh(REMA . Wi + bi); out = sigmoid( (i*tanh(REMAp+ZEMAf)+(1-i)*REMAp) . Wfin )
__global__ void final_kern(const u16* __restrict__ REMAb, const u16* __restrict__ REMApb,
                           const float* __restrict__ ZEMAf,
                           const float* __restrict__ Wi, const float* __restrict__ bi,
                           const float* __restrict__ Wfin, float* __restrict__ out) {
  const int m = blockIdx.x, l = threadIdx.x;
  float si = 0.f;
#pragma unroll
  for (int j = 0; j < 16; ++j) {
    const int n = l + 64 * j;
    si += b2f(REMAb[(size_t)m * 1024 + n]) * Wi[n];
  }
#pragma unroll
  for (int o = 32; o; o >>= 1) si += __shfl_xor(si, o);
  const float im = tanh_fast(si + bi[0]);
  float s = 0.f;
#pragma unroll
  for (int j = 0; j < 16; ++j) {
    const int n = l + 64 * j;
    const float rp = b2f(REMApb[(size_t)m * 1024 + n]);
    const float zf = im * tanh_fast(rp + ZEMAf[(size_t)m * 1024 + n]) + (1.f - im) * rp;
    s += zf * Wfin[n];
  }
#pragma unroll
  for (int o = 32; o; o >>= 1) s += __shfl_down(s, o);
  if (l == 0) out[m] = sigmoid_fast(s);
}

extern "C" void kernel_launch(void* const* d_in, const int* in_sizes, int n_in,
                              void* d_out, int out_size, void* d_ws, size_t ws_size,
                              hipStream_t stream) {
  const float* R       = (const float*)d_in[0];
  const float* W_alpha = (const float*)d_in[1];  const float* b_alpha = (const float*)d_in[2];
  const float* W_delta = (const float*)d_in[3];  const float* b_delta = (const float*)d_in[4];
  const float* W_q     = (const float*)d_in[5];  const float* b_q     = (const float*)d_in[6];
  const float* W_k     = (const float*)d_in[7];  const float* b_k     = (const float*)d_in[8];
  const float* W_v     = (const float*)d_in[9];  const float* b_v     = (const float*)d_in[10];
  const float* W_z     = (const float*)d_in[11]; const float* b_z     = (const float*)d_in[12];
  const float* W_f     = (const float*)d_in[13]; const float* b_f     = (const float*)d_in[14];
  const float* W_EMA   = (const float*)d_in[15]; const float* b_EMA   = (const float*)d_in[16];
  const float* W_z_at  = (const float*)d_in[17]; const float* b_z_at  = (const float*)d_in[18];
  const float* W_i     = (const float*)d_in[19]; const float* b_i     = (const float*)d_in[20];
  const float* W_final = (const float*)d_in[21];
  float* out = (float*)d_out;
  uint8_t* w8 = (uint8_t*)d_ws;

  // ---- workspace layout (time-multiplexed), peak ~110 MB ----
  u16*   Rc     = (u16*)(w8 + 0 * MB);     // [0,16)  prep -> adGEMM
  u16*   Zb     = (u16*)(w8 + 0 * MB);     // [0,8)   zre -> qkvf
  u16*   Zatpb  = (u16*)(w8 + 0 * MB);     // [0,8)   PV -> zemaf
  u16*   REMApb = (u16*)(w8 + 8 * MB);     // [8,16)  zre -> final
  u16*   Wad    = (u16*)(w8 + 16 * MB);    // [16,24) prep -> adGEMM (interleaved)
  u16*   fvb    = (u16*)(w8 + 16 * MB);    // [16,24) qkvf -> PV
  float* ZEMAf  = (float*)(w8 + 24 * MB);  // [24,40) zemaf -> final
  u16*   Wqkv   = (u16*)(w8 + 40 * MB);    // [40,46) prep -> qkvf
  u16*   Vtb    = (u16*)(w8 + 40 * MB);    // [40,48) transpose -> PV
  u16*   Wze    = (u16*)(w8 + 46 * MB);    // [46,50) prep -> zre
  u16*   Wfb    = (u16*)(w8 + 50 * MB);    // [50,52) prep -> qkvf(f)
  u16*   Wzab   = (u16*)(w8 + 52 * MB);    // [52,54) prep -> zemaf
  u16*   REMAb  = (u16*)(w8 + 54 * MB);    // [54,62) adGEMM -> end
  u16*   QKb    = (u16*)(w8 + 62 * MB);    // [62,78) qkvf -> scores
  u16*   Vb     = (u16*)(w8 + 78 * MB);    // [78,86) qkvf -> transpose
  u16*   Sb     = (u16*)(w8 + 78 * MB);    // [78,110) scores -> PV
  float* bad    = (float*)(w8 + 110 * MB + 64 * 1024);
  float* bze    = bad + 2048;
  float* bqkv   = bze + 2048;

  const dim3 blk(256);
  convert_all<<<19456, blk, 0, stream>>>(W_alpha, W_delta, W_z, W_EMA, W_q, W_k, W_v, W_f, W_z_at,
                                         R, Wad, Wze, Wqkv, Wfb, Wzab, Rc);
  copy_bias<<<7, blk, 0, stream>>>(b_alpha, b_delta, b_z, b_EMA, b_q, b_k, b_v, bad, bze, bqkv);

  // ad + fused EMA: REMAb = alpha*r_t + (1-alpha)*delta*r_prev   (1024 blocks)
  gemm<M_EMA><<<dim3(16, 64), blk, 0, stream>>>(
      Rc, Wad, bad, nullptr, nullptr, nullptr, nullptr, REMAb, nullptr, nullptr, nullptr, R, 2048, 2048, 2048, 1.f);
  // Z | REMAp fused: N=2048 (silu -> Zb, plain -> REMApb)   (1024 blocks)
  gemm<M_ZRE><<<dim3(16, 64), blk, 0, stream>>>(
      REMAb, Wze, bze, nullptr, nullptr, nullptr, nullptr, Zb, REMApb, nullptr, nullptr, nullptr, 1024, 1024, 1024, 1.f);
  // QKV + f merged: virtual N=4096 (QK->QKb, V->Vb, f->fvb)   (2048 blocks)
  gemm<M_QKVF><<<dim3(32, 64), blk, 0, stream>>>(
      Zb, Wqkv, bqkv, REMApb, Wfb, b_f, nullptr, QKb, Vb, fvb, nullptr, nullptr, 1024, 1024, 1024, 1.f);
  transpose_b16<<<dim3(16, 64), blk, 0, stream>>>(Vb, Vtb);
  // scores (2048 blocks)
  gemm<M_SCALE><<<dim3(32, 64), blk, 0, stream>>>(
      QKb, QKb + 1024, nullptr, nullptr, nullptr, nullptr, nullptr, Sb, nullptr, nullptr, nullptr, nullptr, 1024, 2048, 2048, 0.03125f);
  softmax_rows<<<4096, blk, 0, stream>>>(Sb);
  // PV with fused f-gate: Zatp = f * (P @ Vt)   (512 blocks, K=4096)
  gemm<M_PVMUL><<<dim3(8, 64), blk, 0, stream>>>(
      Sb, Vtb, nullptr, nullptr, nullptr, nullptr, fvb, Zatpb, nullptr, nullptr, nullptr, nullptr, 4096, 4096, 4096, 1.f);
  // Z_EMA_f (f32)   (512 blocks)
  gemm<M_F32><<<dim3(8, 64), blk, 0, stream>>>(
      Zatpb, Wzab, b_z_at, nullptr, nullptr, nullptr, nullptr, nullptr, nullptr, nullptr, ZEMAf, nullptr, 1024, 1024, 1024, 1.f);
  // fused i + final
  final_kern<<<4096, 64, 0, stream>>>(REMAb, REMApb, ZEMAf, W_i, b_i, W_final, out);
}

// Round 13
// 324.798 us; speedup vs baseline: 1.0487x; 1.0487x over previous
//
#include <hip/hip_runtime.h>
#include <cstdint>
#include <cmath>

#define MB (1024ull * 1024ull)

typedef unsigned short u16;
typedef __attribute__((ext_vector_type(8))) short short8;
typedef __attribute__((ext_vector_type(4))) float f32x4;

enum { M_EMA = 0, M_ZRE = 1, M_QKVF = 2, M_SCALE = 3, M_PVMUL = 4, M_F32 = 5 };

__device__ __forceinline__ u16 f2b(float f) {
  union { float f; uint32_t u; } v; v.f = f;
  uint32_t r = v.u + 0x7FFFu + ((v.u >> 16) & 1u);
  return (u16)(r >> 16);
}
__device__ __forceinline__ float b2f(u16 u) {
  union { uint32_t u; float f; } v; v.u = ((uint32_t)u) << 16;
  return v.f;
}
__device__ __forceinline__ float tanh_fast(float x) {
  return 1.f - 2.f / (1.f + __expf(2.f * x));
}
__device__ __forceinline__ float sigmoid_fast(float x) {
  return 1.f / (1.f + __expf(-x));
}

typedef __attribute__((address_space(3))) uint32_t lds_u32;
typedef const __attribute__((address_space(1))) uint32_t glb_u32;

__device__ __forceinline__ void gload16(const void* g, void* l) {
  __builtin_amdgcn_global_load_lds((glb_u32*)g, (lds_u32*)l, 16, 0, 0);
}

// ---------------- MFMA GEMM (round-11 structure): C = epi(A @ B^T [+ bias]) ----------------
// 64 x 128 tile, 4 waves (1x4, 64r x 32c each), BK=32, 2-buffer LDS, stage(t+1)
// issued before compute(t), one __syncthreads per K-step. Chunk-XOR LDS swizzle.
// M_EMA: Wad/bias interleaved (alpha even col, delta odd col); epilogue pairs lanes
//        via shfl_xor(1); even lane computes REMA from R (fp32) -> Cb bf16.
// M_QKVF: virtual N=4096; bn>=3072 -> f=sigmoid(A2@B2^T+bias2) -> Cb3;
//         bn in [2048,3072) -> V block: epilogue transposes via LDS -> Cb2 = Vt[1024][4096].
// M_PVMUL: epilogue v *= aux (f-gate) -> Cb.
template <int MODE>
__global__ __launch_bounds__(256) void gemm(const u16* __restrict__ A,
                                            const u16* __restrict__ B,
                                            const float* __restrict__ bias,
                                            const u16* __restrict__ A2,
                                            const u16* __restrict__ B2,
                                            const float* __restrict__ bias2,
                                            const u16* __restrict__ auxb,
                                            u16* __restrict__ Cb,
                                            u16* __restrict__ Cb2,
                                            u16* __restrict__ Cb3,
                                            float* __restrict__ Cf,
                                            const float* __restrict__ R,
                                            int K, int lda, int ldb, float scale) {
  constexpr int NI = 4;
  constexpr int NJ = 2;
  // single pool: As[2] at [0,4096), Bs[2] at [4096,12288) u16; V-transpose tile
  // T[128][72] (9216 u16) reuses the pool after the K-loop's final barrier.
  __shared__ __align__(16) u16 smem[12288];
  const int tid = threadIdx.x;
  const int wid = tid >> 6, lane = tid & 63;

  // XCD-aware bijective block swizzle (grids are multiples of 8)
  const int gx = gridDim.x, nwg = gx * gridDim.y;
  int id = blockIdx.y * gx + blockIdx.x;
  if ((nwg & 7) == 0) id = (id & 7) * (nwg >> 3) + (id >> 3);
  const int bm = (id / gx) * 64, bn = (id % gx) * 128;
  const int colbase = wid * 32;

  const bool isf = (MODE == M_QKVF) && (bn >= 3072);
  const u16* Ab = isf ? A2 : A;
  const u16* Bb = isf ? B2 : B;
  const int bnl = isf ? bn - 3072 : bn;

  // staging: thread t -> row srow, swizzled 8-elem chunk
  const int srow = tid >> 2;
  const int schunk = (tid & 3) ^ ((srow >> 1) & 3);
  const u16* gA = Ab + (size_t)(bm + srow) * lda + schunk * 8;
  const u16* gB = Bb + (size_t)(bnl + srow) * ldb + schunk * 8;

  f32x4 acc[NI][NJ];
#pragma unroll
  for (int i = 0; i < NI; ++i)
#pragma unroll
    for (int j = 0; j < NJ; ++j) acc[i][j] = (f32x4){0.f, 0.f, 0.f, 0.f};

  const int ar = lane & 15;
  const int pch = (((lane >> 4) ^ ((ar >> 1) & 3))) * 8;  // swizzled k-chunk

  const int NT = K >> 5;

  auto stage = [&](int buf, int t) {
    const u16* a = gA + (size_t)t * 32;
    const u16* b = gB + (size_t)t * 32;
    gload16(a, &smem[buf * 2048 + wid * 512]);
    gload16(b, &smem[4096 + buf * 4096 + wid * 512]);
    gload16(b + (size_t)64 * ldb, &smem[4096 + buf * 4096 + wid * 512 + 2048]);
  };

  stage(0, 0);
  __syncthreads();
  int cur = 0;
  for (int t = 0; t < NT; ++t) {
    if (t + 1 < NT) stage(cur ^ 1, t + 1);  // prefetch overlaps compute below
    const u16* Asb = &smem[cur * 2048];
    const u16* Bsb = &smem[4096 + cur * 4096];
    short8 af[NI], bf[NJ];
#pragma unroll
    for (int i = 0; i < NI; ++i)
      af[i] = *reinterpret_cast<const short8*>(&Asb[(i * 16 + ar) * 32 + pch]);
#pragma unroll
    for (int j = 0; j < NJ; ++j)
      bf[j] = *reinterpret_cast<const short8*>(&Bsb[(colbase + j * 16 + ar) * 32 + pch]);
    __builtin_amdgcn_s_setprio(1);
#pragma unroll
    for (int i = 0; i < NI; ++i)
#pragma unroll
      for (int j = 0; j < NJ; ++j)
        acc[i][j] = __builtin_amdgcn_mfma_f32_16x16x32_bf16(af[i], bf[j], acc[i][j], 0, 0, 0);
    __builtin_amdgcn_s_setprio(0);
    __syncthreads();
    cur ^= 1;
  }

  // ---- V block: transpose through LDS, write Vt[1024][4096] coalesced ----
  if (MODE == M_QKVF && !isf && bn >= 2048) {
    u16 (*T)[72] = (u16(*)[72])smem;  // pool dead after final barrier
#pragma unroll
    for (int i = 0; i < NI; ++i) {
      const int rl0 = i * 16 + (lane >> 4) * 4;
#pragma unroll
      for (int j = 0; j < NJ; ++j) {
        const int cl = colbase + j * 16 + ar;
        const float bv = bias[bn + cl];
        ushort4 o;
        o.x = f2b(acc[i][j][0] + bv); o.y = f2b(acc[i][j][1] + bv);
        o.z = f2b(acc[i][j][2] + bv); o.w = f2b(acc[i][j][3] + bv);
        *reinterpret_cast<ushort4*>(&T[cl][rl0]) = o;
      }
    }
    __syncthreads();
#pragma unroll
    for (int l = 0; l < 4; ++l) {
      const int slot = l * 256 + tid;     // 128 rows x 8 chunks
      const int row = slot >> 3, ch = slot & 7;
      const short8 val = *reinterpret_cast<const short8*>(&T[row][ch * 8]);
      *reinterpret_cast<short8*>(&Cb2[(size_t)(bn - 2048 + row) * 4096 + bm + ch * 8]) = val;
    }
    return;
  }

#pragma unroll
  for (int i = 0; i < NI; ++i) {
    const int rb = bm + i * 16 + (lane >> 4) * 4;
#pragma unroll
    for (int j = 0; j < NJ; ++j) {
      const int n = bn + colbase + j * 16 + ar;
#pragma unroll
      for (int r = 0; r < 4; ++r) {
        const int m = rb + r;
        float v = acc[i][j][r];
        if (MODE == M_EMA) {
          v = tanh_fast(v + bias[n]);
          const float vp = __shfl_xor(v, 1);
          if ((lane & 1) == 0) {
            const int jc = n >> 1;
            const float rt = R[(size_t)m * 1024 + jc];
            const float rp = (m > 0) ? R[(size_t)(m - 1) * 1024 + jc] : 0.f;
            const float rema = v * rt + (1.f - v) * vp * rp;
            Cb[(size_t)m * 1024 + jc] = f2b(rema);
          }
        } else if (MODE == M_ZRE) {
          v += bias[n];
          if (n < 1024) Cb[(size_t)m * 1024 + n] = f2b(v * sigmoid_fast(v));
          else Cb2[(size_t)m * 1024 + (n - 1024)] = f2b(v);
        } else if (MODE == M_QKVF) {
          if (isf) {
            const int nl = n - 3072;
            Cb3[(size_t)m * 1024 + nl] = f2b(sigmoid_fast(v + bias2[nl]));
          } else {
            v += bias[n];
            Cb[(size_t)m * 2048 + n] = f2b(v);  // QK block (n < 2048 here)
          }
        } else if (MODE == M_SCALE) {
          Cb[(size_t)m * 4096 + n] = f2b(v * scale);
        } else if (MODE == M_PVMUL) {
          v *= b2f(auxb[(size_t)m * 1024 + n]);
          Cb[(size_t)m * 1024 + n] = f2b(v);
        } else if (MODE == M_F32) {
          Cf[(size_t)m * 1024 + n] = v + bias[n];
        }
      }
    }
  }
}

// ---------------- merged prep: weight conversions (Wad interleaved) + concat + biases ----------------
__global__ __launch_bounds__(256) void convert_all(
    const float* __restrict__ s0, const float* __restrict__ s1, const float* __restrict__ s2,
    const float* __restrict__ s3, const float* __restrict__ s4, const float* __restrict__ s5,
    const float* __restrict__ s6, const float* __restrict__ s7, const float* __restrict__ s8,
    const float* __restrict__ R,
    const float* __restrict__ ba, const float* __restrict__ bdl, const float* __restrict__ bz,
    const float* __restrict__ be, const float* __restrict__ bq, const float* __restrict__ bk_,
    const float* __restrict__ bv,
    u16* __restrict__ Wad, u16* __restrict__ Wze, u16* __restrict__ Wqkv,
    u16* __restrict__ Wfb, u16* __restrict__ Wzab, u16* __restrict__ Rc,
    float* __restrict__ bad, float* __restrict__ bze, float* __restrict__ bqkv) {
  const int idx = blockIdx.x * 256 + threadIdx.x;
  if (idx >= 4980736) {
    const int k = idx - 4980736;
    if (k >= 7168) return;
    if      (k < 1024) bad[2 * k] = ba[k];
    else if (k < 2048) bad[2 * (k - 1024) + 1] = bdl[k - 1024];
    else if (k < 3072) bze[k - 2048] = bz[k - 2048];
    else if (k < 4096) bze[1024 + (k - 3072)] = be[k - 3072];
    else if (k < 5120) bqkv[k - 4096] = bq[k - 4096];
    else if (k < 6144) bqkv[1024 + (k - 5120)] = bk_[k - 5120];
    else               bqkv[2048 + (k - 6144)] = bv[k - 6144];
    return;
  }
  if (idx >= 2883584) {
    const int off = idx - 2883584;
    const int m = off >> 9;
    const int c = (off & 511) * 4;
    float4 v;
    if (c < 1024) {
      if (m > 0) v = *reinterpret_cast<const float4*>(&R[(size_t)(m - 1) * 1024 + c]);
      else v = make_float4(0.f, 0.f, 0.f, 0.f);
    } else {
      v = *reinterpret_cast<const float4*>(&R[(size_t)m * 1024 + (c - 1024)]);
    }
    ushort4 o; o.x = f2b(v.x); o.y = f2b(v.y); o.z = f2b(v.z); o.w = f2b(v.w);
    reinterpret_cast<ushort4*>(Rc)[off] = o;
    return;
  }
  const float* src; u16* dst; int off; int dstoff = -1;
  if (idx < 524288) {
    src = s0; dst = Wad; off = idx;
    dstoff = ((off >> 9) * 2) * 512 + (off & 511);
  } else if (idx < 1048576) {
    src = s1; dst = Wad; off = idx - 524288;
    dstoff = ((off >> 9) * 2 + 1) * 512 + (off & 511);
  }
  else if (idx < 1310720) { src = s2; dst = Wze;            off = idx - 1048576; }
  else if (idx < 1572864) { src = s3; dst = Wze + 1048576;  off = idx - 1310720; }
  else if (idx < 1835008) { src = s4; dst = Wqkv;           off = idx - 1572864; }
  else if (idx < 2097152) { src = s5; dst = Wqkv + 1048576; off = idx - 1835008; }
  else if (idx < 2359296) { src = s6; dst = Wqkv + 2097152; off = idx - 2097152; }
  else if (idx < 2621440) { src = s7; dst = Wfb;            off = idx - 2359296; }
  else                    { src = s8; dst = Wzab;           off = idx - 2621440; }
  if (dstoff < 0) dstoff = off;
  const float4 v = reinterpret_cast<const float4*>(src)[off];
  ushort4 o; o.x = f2b(v.x); o.y = f2b(v.y); o.z = f2b(v.z); o.w = f2b(v.w);
  reinterpret_cast<ushort4*>(dst)[dstoff] = o;
}

__device__ __forceinline__ float waveMax(float v) {
#pragma unroll
  for (int o = 32; o; o >>= 1) v = fmaxf(v, __shfl_down(v, o));
  return v;
}
__device__ __forceinline__ float waveSum(float v) {
#pragma unroll
  for (int o = 32; o; o >>= 1) v += __shfl_down(v, o);
  return v;
}

__global__ __launch_bounds__(256) void softmax_rows(u16* __restrict__ S) {
  u16* p = S + (size_t)blockIdx.x * 4096;
  const int tid = threadIdx.x;
  float v[16];
#pragma unroll
  for (int j = 0; j < 4; ++j) {
    const ushort4 t = *reinterpret_cast<const ushort4*>(&p[tid * 4 + 1024 * j]);
    v[4 * j + 0] = b2f(t.x); v[4 * j + 1] = b2f(t.y);
    v[4 * j + 2] = b2f(t.z); v[4 * j + 3] = b2f(t.w);
  }
  float mx = -INFINITY;
#pragma unroll
  for (int j = 0; j < 16; ++j) mx = fmaxf(mx, v[j]);
  __shared__ float red[4];
  const float wm = waveMax(mx);
  if ((tid & 63) == 0) red[tid >> 6] = wm;
  __syncthreads();
  mx = fmaxf(fmaxf(red[0], red[1]), fmaxf(red[2], red[3]));
  __syncthreads();
  float sum = 0.f;
#pragma unroll
  for (int j = 0; j < 16; ++j) { v[j] = __expf(v[j] - mx); sum += v[j]; }
  const float ws_ = waveSum(sum);
  if ((tid & 63) == 0) red[tid >> 6] = ws_;
  __syncthreads();
  const float inv = 1.f / (red[0] + red[1] + red[2] + red[3]);
#pragma unroll
  for (int j = 0; j < 4; ++j) {
    ushort4 t;
    t.x = f2b(v[4 * j + 0] * inv); t.y = f2b(v[4 * j + 1] * inv);
    t.z = f2b(v[4 * j + 2] * inv); t.w = f2b(v[4 * j + 3] * inv);
    *reinterpret_cast<ushort4*>(&p[tid * 4 + 1024 * j]) = t;
  }
}

// fused: i = tanh(REMA . Wi + bi); out = sigmoid( (i*tanh(REMAp+ZEMAf)+(1-i)*REMAp) . Wfin )
__global__ void final_kern(const u16* __restrict__ REMAb, const u16* __restrict__ REMApb,
                           const float* __restrict__ ZEMAf,
                           const float* __restrict__ Wi, const float* __restrict__ bi,
                           const float* __restrict__ Wfin, float* __restrict__ out) {
  const int m = blockIdx.x, l = threadIdx.x;
  float si = 0.f;
#pragma unroll
  for (int j = 0; j < 16; ++j) {
    const int n = l + 64 * j;
    si += b2f(REMAb[(size_t)m * 1024 + n]) * Wi[n];
  }
#pragma unroll
  for (int o = 32; o; o >>= 1) si += __shfl_xor(si, o);
  const float im = tanh_fast(si + bi[0]);
  float s = 0.f;
#pragma unroll
  for (int j = 0; j < 16; ++j) {
    const int n = l + 64 * j;
    const float rp = b2f(REMApb[(size_t)m * 1024 + n]);
    const float zf = im * tanh_fast(rp + ZEMAf[(size_t)m * 1024 + n]) + (1.f - im) * rp;
    s += zf * Wfin[n];
  }
#pragma unroll
  for (int o = 32; o; o >>= 1) s += __shfl_down(s, o);
  if (l == 0) out[m] = sigmoid_fast(s);
}

extern "C" void kernel_launch(void* const* d_in, const int* in_sizes, int n_in,
                              void* d_out, int out_size, void* d_ws, size_t ws_size,
                              hipStream_t stream) {
  const float* R       = (const float*)d_in[0];
  const float* W_alpha = (const float*)d_in[1];  const float* b_alpha = (const float*)d_in[2];
  const float* W_delta = (const float*)d_in[3];  const float* b_delta = (const float*)d_in[4];
  const float* W_q     = (const float*)d_in[5];  const float* b_q     = (const float*)d_in[6];
  const float* W_k     = (const float*)d_in[7];  const float* b_k     = (const float*)d_in[8];
  const float* W_v     = (const float*)d_in[9];  const float* b_v     = (const float*)d_in[10];
  const float* W_z     = (const float*)d_in[11]; const float* b_z     = (const float*)d_in[12];
  const float* W_f     = (const float*)d_in[13]; const float* b_f     = (const float*)d_in[14];
  const float* W_EMA   = (const float*)d_in[15]; const float* b_EMA   = (const float*)d_in[16];
  const float* W_z_at  = (const float*)d_in[17]; const float* b_z_at  = (const float*)d_in[18];
  const float* W_i     = (const float*)d_in[19]; const float* b_i     = (const float*)d_in[20];
  const float* W_final = (const float*)d_in[21];
  float* out = (float*)d_out;
  uint8_t* w8 = (uint8_t*)d_ws;

  // ---- workspace layout (time-multiplexed), peak ~110 MB ----
  u16*   Rc     = (u16*)(w8 + 0 * MB);     // [0,16)  prep -> adGEMM
  u16*   Zb     = (u16*)(w8 + 0 * MB);     // [0,8)   zre -> qkvf
  u16*   Zatpb  = (u16*)(w8 + 0 * MB);     // [0,8)   PV -> zemaf
  u16*   REMApb = (u16*)(w8 + 8 * MB);     // [8,16)  zre -> final
  u16*   Wad    = (u16*)(w8 + 16 * MB);    // [16,24) prep -> adGEMM (interleaved)
  u16*   fvb    = (u16*)(w8 + 16 * MB);    // [16,24) qkvf -> PV
  u16*   Vtb    = (u16*)(w8 + 24 * MB);    // [24,32) qkvf -> PV
  float* ZEMAf  = (float*)(w8 + 24 * MB);  // [24,40) zemaf -> final (post-PV, Vt dead)
  u16*   Wqkv   = (u16*)(w8 + 40 * MB);    // [40,46) prep -> qkvf
  u16*   Wze    = (u16*)(w8 + 46 * MB);    // [46,50) prep -> zre
  u16*   Wfb    = (u16*)(w8 + 50 * MB);    // [50,52) prep -> qkvf(f)
  u16*   Wzab   = (u16*)(w8 + 52 * MB);    // [52,54) prep -> zemaf
  u16*   REMAb  = (u16*)(w8 + 54 * MB);    // [54,62) adGEMM -> end
  u16*   QKb    = (u16*)(w8 + 62 * MB);    // [62,78) qkvf -> scores
  u16*   Sb     = (u16*)(w8 + 78 * MB);    // [78,110) scores -> PV
  float* bad    = (float*)(w8 + 110 * MB + 64 * 1024);
  float* bze    = bad + 2048;
  float* bqkv   = bze + 2048;

  const dim3 blk(256);
  // prep: weights + concat + biases in one launch (19484 blocks)
  convert_all<<<19484, blk, 0, stream>>>(W_alpha, W_delta, W_z, W_EMA, W_q, W_k, W_v, W_f, W_z_at,
                                         R, b_alpha, b_delta, b_z, b_EMA, b_q, b_k, b_v,
                                         Wad, Wze, Wqkv, Wfb, Wzab, Rc, bad, bze, bqkv);

  // ad + fused EMA: REMAb = alpha*r_t + (1-alpha)*delta*r_prev   (1024 blocks)
  gemm<M_EMA><<<dim3(16, 64), blk, 0, stream>>>(
      Rc, Wad, bad, nullptr, nullptr, nullptr, nullptr, REMAb, nullptr, nullptr, nullptr, R, 2048, 2048, 2048, 1.f);
  // Z | REMAp fused: N=2048 (silu -> Zb, plain -> REMApb)   (1024 blocks)
  gemm<M_ZRE><<<dim3(16, 64), blk, 0, stream>>>(
      REMAb, Wze, bze, nullptr, nullptr, nullptr, nullptr, Zb, REMApb, nullptr, nullptr, nullptr, 1024, 1024, 1024, 1.f);
  // QKV + f merged: virtual N=4096 (QK->QKb, V->transposed Vtb, f->fvb)   (2048 blocks)
  gemm<M_QKVF><<<dim3(32, 64), blk, 0, stream>>>(
      Zb, Wqkv, bqkv, REMApb, Wfb, b_f, nullptr, QKb, Vtb, fvb, nullptr, nullptr, 1024, 1024, 1024, 1.f);
  // scores (2048 blocks)
  gemm<M_SCALE><<<dim3(32, 64), blk, 0, stream>>>(
      QKb, QKb + 1024, nullptr, nullptr, nullptr, nullptr, nullptr, Sb, nullptr, nullptr, nullptr, nullptr, 1024, 2048, 2048, 0.03125f);
  softmax_rows<<<4096, blk, 0, stream>>>(Sb);
  // PV with fused f-gate: Zatp = f * (P @ Vt)   (512 blocks, K=4096)
  gemm<M_PVMUL><<<dim3(8, 64), blk, 0, stream>>>(
      Sb, Vtb, nullptr, nullptr, nullptr, nullptr, fvb, Zatpb, nullptr, nullptr, nullptr, nullptr, 4096, 4096, 4096, 1.f);
  // Z_EMA_f (f32)   (512 blocks)
  gemm<M_F32><<<dim3(8, 64), blk, 0, stream>>>(
      Zatpb, Wzab, b_z_at, nullptr, nullptr, nullptr, nullptr, nullptr, nullptr, nullptr, ZEMAf, nullptr, 1024, 1024, 1024, 1.f);
  // fused i + final
  final_kern<<<4096, 64, 0, stream>>>(REMAb, REMApb, ZEMAf, W_i, b_i, W_final, out);
}

// Round 14
// 323.759 us; speedup vs baseline: 1.0520x; 1.0032x over previous
//
#include <hip/hip_runtime.h>
#include <cstdint>
#include <cmath>

#define MB (1024ull * 1024ull)

typedef unsigned short u16;
typedef __attribute__((ext_vector_type(8))) short short8;
typedef __attribute__((ext_vector_type(8))) unsigned short ushort8;
typedef __attribute__((ext_vector_type(4))) float f32x4;

enum { M_EMA = 0, M_ZRE = 1, M_QKVF = 2, M_SCALE = 3, M_PVMUL = 4, M_ZEF = 5 };

__device__ __forceinline__ u16 f2b(float f) {
  union { float f; uint32_t u; } v; v.f = f;
  uint32_t r = v.u + 0x7FFFu + ((v.u >> 16) & 1u);
  return (u16)(r >> 16);
}
__device__ __forceinline__ float b2f(u16 u) {
  union { uint32_t u; float f; } v; v.u = ((uint32_t)u) << 16;
  return v.f;
}
__device__ __forceinline__ float tanh_fast(float x) {
  return 1.f - 2.f / (1.f + __expf(2.f * x));
}
__device__ __forceinline__ float sigmoid_fast(float x) {
  return 1.f / (1.f + __expf(-x));
}

typedef __attribute__((address_space(3))) uint32_t lds_u32;
typedef const __attribute__((address_space(1))) uint32_t glb_u32;

__device__ __forceinline__ void gload16(const void* g, void* l) {
  __builtin_amdgcn_global_load_lds((glb_u32*)g, (lds_u32*)l, 16, 0, 0);
}

// ---------------- MFMA GEMM (round-11 structure): C = epi(A @ B^T [+ bias]) ----------------
// 64 x 128 tile, 4 waves (1x4, 64r x 32c each), BK=32, 2-buffer LDS, stage(t+1)
// issued before compute(t), one __syncthreads per K-step. Chunk-XOR LDS swizzle.
// M_EMA: Wad/bias interleaved (alpha even col, delta odd col); epilogue pairs lanes
//        via shfl_xor(1); even lane computes REMA from R (fp32) -> Cb bf16.
// M_QKVF: virtual N=4096; bn>=3072 -> f=sigmoid(A2@B2^T+bias2) -> Cb3;
//         bn in [2048,3072) -> V block: epilogue transposes via LDS -> Cb2 = Vt[1024][4096].
// M_PVMUL: epilogue v *= aux (f-gate) -> Cb.
// M_ZEF: bf16 out with bias -> Cb (ZEMAf).
template <int MODE>
__global__ __launch_bounds__(256) void gemm(const u16* __restrict__ A,
                                            const u16* __restrict__ B,
                                            const float* __restrict__ bias,
                                            const u16* __restrict__ A2,
                                            const u16* __restrict__ B2,
                                            const float* __restrict__ bias2,
                                            const u16* __restrict__ auxb,
                                            u16* __restrict__ Cb,
                                            u16* __restrict__ Cb2,
                                            u16* __restrict__ Cb3,
                                            const float* __restrict__ R,
                                            int K, int lda, int ldb, float scale) {
  constexpr int NI = 4;
  constexpr int NJ = 2;
  // single pool: As[2] at [0,4096), Bs[2] at [4096,12288) u16; V-transpose tile
  // T[128][72] (9216 u16) reuses the pool after the K-loop's final barrier.
  __shared__ __align__(16) u16 smem[12288];
  const int tid = threadIdx.x;
  const int wid = tid >> 6, lane = tid & 63;

  // XCD-aware bijective block swizzle (grids are multiples of 8)
  const int gx = gridDim.x, nwg = gx * gridDim.y;
  int id = blockIdx.y * gx + blockIdx.x;
  if ((nwg & 7) == 0) id = (id & 7) * (nwg >> 3) + (id >> 3);
  const int bm = (id / gx) * 64, bn = (id % gx) * 128;
  const int colbase = wid * 32;

  const bool isf = (MODE == M_QKVF) && (bn >= 3072);
  const u16* Ab = isf ? A2 : A;
  const u16* Bb = isf ? B2 : B;
  const int bnl = isf ? bn - 3072 : bn;

  // staging: thread t -> row srow, swizzled 8-elem chunk
  const int srow = tid >> 2;
  const int schunk = (tid & 3) ^ ((srow >> 1) & 3);
  const u16* gA = Ab + (size_t)(bm + srow) * lda + schunk * 8;
  const u16* gB = Bb + (size_t)(bnl + srow) * ldb + schunk * 8;

  f32x4 acc[NI][NJ];
#pragma unroll
  for (int i = 0; i < NI; ++i)
#pragma unroll
    for (int j = 0; j < NJ; ++j) acc[i][j] = (f32x4){0.f, 0.f, 0.f, 0.f};

  const int ar = lane & 15;
  const int pch = (((lane >> 4) ^ ((ar >> 1) & 3))) * 8;  // swizzled k-chunk

  const int NT = K >> 5;

  auto stage = [&](int buf, int t) {
    const u16* a = gA + (size_t)t * 32;
    const u16* b = gB + (size_t)t * 32;
    gload16(a, &smem[buf * 2048 + wid * 512]);
    gload16(b, &smem[4096 + buf * 4096 + wid * 512]);
    gload16(b + (size_t)64 * ldb, &smem[4096 + buf * 4096 + wid * 512 + 2048]);
  };

  stage(0, 0);
  __syncthreads();
  int cur = 0;
  for (int t = 0; t < NT; ++t) {
    if (t + 1 < NT) stage(cur ^ 1, t + 1);  // prefetch overlaps compute below
    const u16* Asb = &smem[cur * 2048];
    const u16* Bsb = &smem[4096 + cur * 4096];
    short8 af[NI], bf[NJ];
#pragma unroll
    for (int i = 0; i < NI; ++i)
      af[i] = *reinterpret_cast<const short8*>(&Asb[(i * 16 + ar) * 32 + pch]);
#pragma unroll
    for (int j = 0; j < NJ; ++j)
      bf[j] = *reinterpret_cast<const short8*>(&Bsb[(colbase + j * 16 + ar) * 32 + pch]);
    __builtin_amdgcn_s_setprio(1);
#pragma unroll
    for (int i = 0; i < NI; ++i)
#pragma unroll
      for (int j = 0; j < NJ; ++j)
        acc[i][j] = __builtin_amdgcn_mfma_f32_16x16x32_bf16(af[i], bf[j], acc[i][j], 0, 0, 0);
    __builtin_amdgcn_s_setprio(0);
    __syncthreads();
    cur ^= 1;
  }

  // ---- V block: transpose through LDS, write Vt[1024][4096] coalesced ----
  if (MODE == M_QKVF && !isf && bn >= 2048) {
    u16 (*T)[72] = (u16(*)[72])smem;  // pool dead after final barrier
#pragma unroll
    for (int i = 0; i < NI; ++i) {
      const int rl0 = i * 16 + (lane >> 4) * 4;
#pragma unroll
      for (int j = 0; j < NJ; ++j) {
        const int cl = colbase + j * 16 + ar;
        const float bv = bias[bn + cl];
        ushort4 o;
        o.x = f2b(acc[i][j][0] + bv); o.y = f2b(acc[i][j][1] + bv);
        o.z = f2b(acc[i][j][2] + bv); o.w = f2b(acc[i][j][3] + bv);
        *reinterpret_cast<ushort4*>(&T[cl][rl0]) = o;
      }
    }
    __syncthreads();
#pragma unroll
    for (int l = 0; l < 4; ++l) {
      const int slot = l * 256 + tid;     // 128 rows x 8 chunks
      const int row = slot >> 3, ch = slot & 7;
      const short8 val = *reinterpret_cast<const short8*>(&T[row][ch * 8]);
      *reinterpret_cast<short8*>(&Cb2[(size_t)(bn - 2048 + row) * 4096 + bm + ch * 8]) = val;
    }
    return;
  }

#pragma unroll
  for (int i = 0; i < NI; ++i) {
    const int rb = bm + i * 16 + (lane >> 4) * 4;
#pragma unroll
    for (int j = 0; j < NJ; ++j) {
      const int n = bn + colbase + j * 16 + ar;
#pragma unroll
      for (int r = 0; r < 4; ++r) {
        const int m = rb + r;
        float v = acc[i][j][r];
        if (MODE == M_EMA) {
          v = tanh_fast(v + bias[n]);
          const float vp = __shfl_xor(v, 1);
          if ((lane & 1) == 0) {
            const int jc = n >> 1;
            const float rt = R[(size_t)m * 1024 + jc];
            const float rp = (m > 0) ? R[(size_t)(m - 1) * 1024 + jc] : 0.f;
            const float rema = v * rt + (1.f - v) * vp * rp;
            Cb[(size_t)m * 1024 + jc] = f2b(rema);
          }
        } else if (MODE == M_ZRE) {
          v += bias[n];
          if (n < 1024) Cb[(size_t)m * 1024 + n] = f2b(v * sigmoid_fast(v));
          else Cb2[(size_t)m * 1024 + (n - 1024)] = f2b(v);
        } else if (MODE == M_QKVF) {
          if (isf) {
            const int nl = n - 3072;
            Cb3[(size_t)m * 1024 + nl] = f2b(sigmoid_fast(v + bias2[nl]));
          } else {
            v += bias[n];
            Cb[(size_t)m * 2048 + n] = f2b(v);  // QK block (n < 2048 here)
          }
        } else if (MODE == M_SCALE) {
          Cb[(size_t)m * 4096 + n] = f2b(v * scale);
        } else if (MODE == M_PVMUL) {
          v *= b2f(auxb[(size_t)m * 1024 + n]);
          Cb[(size_t)m * 1024 + n] = f2b(v);
        } else if (MODE == M_ZEF) {
          Cb[(size_t)m * 1024 + n] = f2b(v + bias[n]);
        }
      }
    }
  }
}

// ---------------- merged prep: weight conversions (Wad interleaved) + concat + biases ----------------
__global__ __launch_bounds__(256) void convert_all(
    const float* __restrict__ s0, const float* __restrict__ s1, const float* __restrict__ s2,
    const float* __restrict__ s3, const float* __restrict__ s4, const float* __restrict__ s5,
    const float* __restrict__ s6, const float* __restrict__ s7, const float* __restrict__ s8,
    const float* __restrict__ R,
    const float* __restrict__ ba, const float* __restrict__ bdl, const float* __restrict__ bz,
    const float* __restrict__ be, const float* __restrict__ bq, const float* __restrict__ bk_,
    const float* __restrict__ bv,
    u16* __restrict__ Wad, u16* __restrict__ Wze, u16* __restrict__ Wqkv,
    u16* __restrict__ Wfb, u16* __restrict__ Wzab, u16* __restrict__ Rc,
    float* __restrict__ bad, float* __restrict__ bze, float* __restrict__ bqkv) {
  const int idx = blockIdx.x * 256 + threadIdx.x;
  if (idx >= 4980736) {
    const int k = idx - 4980736;
    if (k >= 7168) return;
    if      (k < 1024) bad[2 * k] = ba[k];
    else if (k < 2048) bad[2 * (k - 1024) + 1] = bdl[k - 1024];
    else if (k < 3072) bze[k - 2048] = bz[k - 2048];
    else if (k < 4096) bze[1024 + (k - 3072)] = be[k - 3072];
    else if (k < 5120) bqkv[k - 4096] = bq[k - 4096];
    else if (k < 6144) bqkv[1024 + (k - 5120)] = bk_[k - 5120];
    else               bqkv[2048 + (k - 6144)] = bv[k - 6144];
    return;
  }
  if (idx >= 2883584) {
    const int off = idx - 2883584;
    const int m = off >> 9;
    const int c = (off & 511) * 4;
    float4 v;
    if (c < 1024) {
      if (m > 0) v = *reinterpret_cast<const float4*>(&R[(size_t)(m - 1) * 1024 + c]);
      else v = make_float4(0.f, 0.f, 0.f, 0.f);
    } else {
      v = *reinterpret_cast<const float4*>(&R[(size_t)m * 1024 + (c - 1024)]);
    }
    ushort4 o; o.x = f2b(v.x); o.y = f2b(v.y); o.z = f2b(v.z); o.w = f2b(v.w);
    reinterpret_cast<ushort4*>(Rc)[off] = o;
    return;
  }
  const float* src; u16* dst; int off; int dstoff = -1;
  if (idx < 524288) {
    src = s0; dst = Wad; off = idx;
    dstoff = ((off >> 9) * 2) * 512 + (off & 511);
  } else if (idx < 1048576) {
    src = s1; dst = Wad; off = idx - 524288;
    dstoff = ((off >> 9) * 2 + 1) * 512 + (off & 511);
  }
  else if (idx < 1310720) { src = s2; dst = Wze;            off = idx - 1048576; }
  else if (idx < 1572864) { src = s3; dst = Wze + 1048576;  off = idx - 1310720; }
  else if (idx < 1835008) { src = s4; dst = Wqkv;           off = idx - 1572864; }
  else if (idx < 2097152) { src = s5; dst = Wqkv + 1048576; off = idx - 1835008; }
  else if (idx < 2359296) { src = s6; dst = Wqkv + 2097152; off = idx - 2097152; }
  else if (idx < 2621440) { src = s7; dst = Wfb;            off = idx - 2359296; }
  else                    { src = s8; dst = Wzab;           off = idx - 2621440; }
  if (dstoff < 0) dstoff = off;
  const float4 v = reinterpret_cast<const float4*>(src)[off];
  ushort4 o; o.x = f2b(v.x); o.y = f2b(v.y); o.z = f2b(v.z); o.w = f2b(v.w);
  reinterpret_cast<ushort4*>(dst)[dstoff] = o;
}

__device__ __forceinline__ float waveMax(float v) {
#pragma unroll
  for (int o = 32; o; o >>= 1) v = fmaxf(v, __shfl_down(v, o));
  return v;
}
__device__ __forceinline__ float waveSum(float v) {
#pragma unroll
  for (int o = 32; o; o >>= 1) v += __shfl_down(v, o);
  return v;
}

// in-place row softmax, 4096 cols, one block per row, short8 (16B) vector I/O
__global__ __launch_bounds__(256) void softmax_rows(u16* __restrict__ S) {
  u16* p = S + (size_t)blockIdx.x * 4096;
  const int tid = threadIdx.x;
  float v[16];
#pragma unroll
  for (int h = 0; h < 2; ++h) {
    const ushort8 t = *reinterpret_cast<const ushort8*>(&p[tid * 8 + 2048 * h]);
#pragma unroll
    for (int e = 0; e < 8; ++e) v[8 * h + e] = b2f(t[e]);
  }
  float mx = -INFINITY;
#pragma unroll
  for (int j = 0; j < 16; ++j) mx = fmaxf(mx, v[j]);
  __shared__ float red[4];
  const float wm = waveMax(mx);
  if ((tid & 63) == 0) red[tid >> 6] = wm;
  __syncthreads();
  mx = fmaxf(fmaxf(red[0], red[1]), fmaxf(red[2], red[3]));
  __syncthreads();
  float sum = 0.f;
#pragma unroll
  for (int j = 0; j < 16; ++j) { v[j] = __expf(v[j] - mx); sum += v[j]; }
  const float ws_ = waveSum(sum);
  if ((tid & 63) == 0) red[tid >> 6] = ws_;
  __syncthreads();
  const float inv = 1.f / (red[0] + red[1] + red[2] + red[3]);
#pragma unroll
  for (int h = 0; h < 2; ++h) {
    ushort8 t;
#pragma unroll
    for (int e = 0; e < 8; ++e) t[e] = f2b(v[8 * h + e] * inv);
    *reinterpret_cast<ushort8*>(&p[tid * 8 + 2048 * h]) = t;
  }
}

// fused: i = tanh(REMA . Wi + bi); out = sigmoid( (i*tanh(REMAp+ZEMAf)+(1-i)*REMAp) . Wfin )
__global__ void final_kern(const u16* __restrict__ REMAb, const u16* __restrict__ REMApb,
                           const u16* __restrict__ ZEMAfb,
                           const float* __restrict__ Wi, const float* __restrict__ bi,
                           const float* __restrict__ Wfin, float* __restrict__ out) {
  const int m = blockIdx.x, l = threadIdx.x;
  float si = 0.f;
#pragma unroll
  for (int j = 0; j < 16; ++j) {
    const int n = l + 64 * j;
    si += b2f(REMAb[(size_t)m * 1024 + n]) * Wi[n];
  }
#pragma unroll
  for (int o = 32; o; o >>= 1) si += __shfl_xor(si, o);
  const float im = tanh_fast(si + bi[0]);
  float s = 0.f;
#pragma unroll
  for (int j = 0; j < 16; ++j) {
    const int n = l + 64 * j;
    const float rp = b2f(REMApb[(size_t)m * 1024 + n]);
    const float zf = im * tanh_fast(rp + b2f(ZEMAfb[(size_t)m * 1024 + n])) + (1.f - im) * rp;
    s += zf * Wfin[n];
  }
#pragma unroll
  for (int o = 32; o; o >>= 1) s += __shfl_down(s, o);
  if (l == 0) out[m] = sigmoid_fast(s);
}

extern "C" void kernel_launch(void* const* d_in, const int* in_sizes, int n_in,
                              void* d_out, int out_size, void* d_ws, size_t ws_size,
                              hipStream_t stream) {
  const float* R       = (const float*)d_in[0];
  const float* W_alpha = (const float*)d_in[1];  const float* b_alpha = (const float*)d_in[2];
  const float* W_delta = (const float*)d_in[3];  const float* b_delta = (const float*)d_in[4];
  const float* W_q     = (const float*)d_in[5];  const float* b_q     = (const float*)d_in[6];
  const float* W_k     = (const float*)d_in[7];  const float* b_k     = (const float*)d_in[8];
  const float* W_v     = (const float*)d_in[9];  const float* b_v     = (const float*)d_in[10];
  const float* W_z     = (const float*)d_in[11]; const float* b_z     = (const float*)d_in[12];
  const float* W_f     = (const float*)d_in[13]; const float* b_f     = (const float*)d_in[14];
  const float* W_EMA   = (const float*)d_in[15]; const float* b_EMA   = (const float*)d_in[16];
  const float* W_z_at  = (const float*)d_in[17]; const float* b_z_at  = (const float*)d_in[18];
  const float* W_i     = (const float*)d_in[19]; const float* b_i     = (const float*)d_in[20];
  const float* W_final = (const float*)d_in[21];
  float* out = (float*)d_out;
  uint8_t* w8 = (uint8_t*)d_ws;

  // ---- workspace layout (time-multiplexed), peak ~110 MB ----
  u16*   Rc     = (u16*)(w8 + 0 * MB);     // [0,16)  prep -> adGEMM
  u16*   Zb     = (u16*)(w8 + 0 * MB);     // [0,8)   zre -> qkvf
  u16*   Zatpb  = (u16*)(w8 + 0 * MB);     // [0,8)   PV -> zemaf
  u16*   REMApb = (u16*)(w8 + 8 * MB);     // [8,16)  zre -> final
  u16*   Wad    = (u16*)(w8 + 16 * MB);    // [16,24) prep -> adGEMM (interleaved)
  u16*   fvb    = (u16*)(w8 + 16 * MB);    // [16,24) qkvf -> PV
  u16*   Vtb    = (u16*)(w8 + 24 * MB);    // [24,32) qkvf -> PV
  u16*   ZEMAfb = (u16*)(w8 + 24 * MB);    // [24,32) zemaf -> final (post-PV, Vt dead)
  u16*   Wqkv   = (u16*)(w8 + 40 * MB);    // [40,46) prep -> qkvf
  u16*   Wze    = (u16*)(w8 + 46 * MB);    // [46,50) prep -> zre
  u16*   Wfb    = (u16*)(w8 + 50 * MB);    // [50,52) prep -> qkvf(f)
  u16*   Wzab   = (u16*)(w8 + 52 * MB);    // [52,54) prep -> zemaf
  u16*   REMAb  = (u16*)(w8 + 54 * MB);    // [54,62) adGEMM -> end
  u16*   QKb    = (u16*)(w8 + 62 * MB);    // [62,78) qkvf -> scores
  u16*   Sb     = (u16*)(w8 + 78 * MB);    // [78,110) scores -> PV
  float* bad    = (float*)(w8 + 110 * MB + 64 * 1024);
  float* bze    = bad + 2048;
  float* bqkv   = bze + 2048;

  const dim3 blk(256);
  // prep: weights + concat + biases in one launch (19484 blocks)
  convert_all<<<19484, blk, 0, stream>>>(W_alpha, W_delta, W_z, W_EMA, W_q, W_k, W_v, W_f, W_z_at,
                                         R, b_alpha, b_delta, b_z, b_EMA, b_q, b_k, b_v,
                                         Wad, Wze, Wqkv, Wfb, Wzab, Rc, bad, bze, bqkv);

  // ad + fused EMA: REMAb = alpha*r_t + (1-alpha)*delta*r_prev   (1024 blocks)
  gemm<M_EMA><<<dim3(16, 64), blk, 0, stream>>>(
      Rc, Wad, bad, nullptr, nullptr, nullptr, nullptr, REMAb, nullptr, nullptr, R, 2048, 2048, 2048, 1.f);
  // Z | REMAp fused: N=2048 (silu -> Zb, plain -> REMApb)   (1024 blocks)
  gemm<M_ZRE><<<dim3(16, 64), blk, 0, stream>>>(
      REMAb, Wze, bze, nullptr, nullptr, nullptr, nullptr, Zb, REMApb, nullptr, nullptr, 1024, 1024, 1024, 1.f);
  // QKV + f merged: virtual N=4096 (QK->QKb, V->transposed Vtb, f->fvb)   (2048 blocks)
  gemm<M_QKVF><<<dim3(32, 64), blk, 0, stream>>>(
      Zb, Wqkv, bqkv, REMApb, Wfb, b_f, nullptr, QKb, Vtb, fvb, nullptr, 1024, 1024, 1024, 1.f);
  // scores (2048 blocks)
  gemm<M_SCALE><<<dim3(32, 64), blk, 0, stream>>>(
      QKb, QKb + 1024, nullptr, nullptr, nullptr, nullptr, nullptr, Sb, nullptr, nullptr, nullptr, 1024, 2048, 2048, 0.03125f);
  softmax_rows<<<4096, blk, 0, stream>>>(Sb);
  // PV with fused f-gate: Zatp = f * (P @ Vt)   (512 blocks, K=4096)
  gemm<M_PVMUL><<<dim3(8, 64), blk, 0, stream>>>(
      Sb, Vtb, nullptr, nullptr, nullptr, nullptr, fvb, Zatpb, nullptr, nullptr, nullptr, 4096, 4096, 4096, 1.f);
  // Z_EMA_f (bf16 out)   (512 blocks)
  gemm<M_ZEF><<<dim3(8, 64), blk, 0, stream>>>(
      Zatpb, Wzab, b_z_at, nullptr, nullptr, nullptr, nullptr, ZEMAfb, nullptr, nullptr, nullptr, 1024, 1024, 1024, 1.f);
  // fused i + final
  final_kern<<<4096, 64, 0, stream>>>(REMAb, REMApb, ZEMAfb, W_i, b_i, W_final, out);
}